// Round 2
// baseline (2137.237 us; speedup 1.0000x reference)
//
#include <hip/hip_runtime.h>
#include <hip/hip_bf16.h>

typedef unsigned short u16;
typedef unsigned int u32;
typedef __bf16 bf16x8 __attribute__((ext_vector_type(8)));
typedef float f32x4 __attribute__((ext_vector_type(4)));

// output element offsets (f32 elements)
#define OUT_POOLED 0
#define OUT_MEM    6291456
#define OUT_STATE  56623104
#define OUT_HOLD   65011712
#define OUT_ROUTE  65208320

__device__ __forceinline__ float b2f(u16 u){ u32 v=((u32)u)<<16; float f; __builtin_memcpy(&f,&v,4); return f; }
__device__ __forceinline__ u16 f2b(float f){ __hip_bfloat16 h=__float2bfloat16(f); u16 r; __builtin_memcpy(&r,&h,2); return r; }
__device__ __forceinline__ float sigf(float x){ return __builtin_amdgcn_rcpf(1.0f+__builtin_amdgcn_exp2f(-1.4426950408889634f*x)); }
__device__ __forceinline__ float tanh_(float x){ return 1.0f-2.0f*__builtin_amdgcn_rcpf(1.0f+__builtin_amdgcn_exp2f(2.8853900817779268f*x)); }
__device__ __forceinline__ float geluf(float x){
  float z = 0.7071067811865476f*x;
  float az = __builtin_fabsf(z);
  float t = __builtin_amdgcn_rcpf(1.0f+0.3275911f*az);
  float p = t*(0.254829592f+t*(-0.284496736f+t*(1.421413741f+t*(-1.453152027f+t*1.061405429f))));
  float e = __builtin_amdgcn_exp2f(-1.4426950408889634f*az*az);
  float er = 1.0f-p*e;
  er = (z<0.0f)? -er : er;
  return 0.5f*x*(1.0f+er);
}

// ---------------- prep: wcat pack (bf16), bcat, b_comb ----------------
__global__ void k_prep(const float* __restrict__ Ws, const float* __restrict__ bs,
                       const float* __restrict__ bm, const float* __restrict__ Wm,
                       const float* __restrict__ Wh1, const float* __restrict__ bh1,
                       const float* __restrict__ Wt1, const float* __restrict__ bt1,
                       const float* __restrict__ Wv1, const float* __restrict__ bv1,
                       u16* __restrict__ wcat, float* __restrict__ bcat, float* __restrict__ bcomb)
{
  __shared__ float bmS[768];
  int tid = threadIdx.x;
  for(int i=tid;i<768;i+=256) bmS[i]=bm[i];
  __syncthreads();
  const int total = 768+960+122880;
  for(int idx = blockIdx.x*256+tid; idx<total; idx += gridDim.x*256){
    if(idx<768){
      int d=idx; float acc=bs[d];
      for(int e=0;e<8;e++){
        const float* row = Ws + d*6144 + e*768;
        for(int k0=0;k0<768;k0+=4){
          float4 u = *reinterpret_cast<const float4*>(row+k0);
          acc += u.x*bmS[k0]+u.y*bmS[k0+1]+u.z*bmS[k0+2]+u.w*bmS[k0+3];
        }
      }
      bcomb[d]=acc;
    } else if(idx<1728){
      int n=idx-768;
      float v;
      if(n<768) v=bm[n];
      else { int j=n-768; v = (j<64)? bh1[j] : (j<128)? bt1[j-64] : bv1[j-128]; }
      bcat[n]=v;
    } else {
      int c=idx-1728; int n=c>>7, k=c&127;
      float v;
      if(n<768) v=Wm[n*128+k];
      else if(n<832) v=Wh1[(n-768)*128+k];
      else if(n<896) v=Wt1[(n-832)*128+k];
      else v=Wv1[(n-896)*128+k];
      wcat[c]=f2b(v);
    }
  }
}

// ---------------- Wcomb[d][e*128+s] = sum_d2 Ws[d][e*768+d2]*Wm[d2][s] (bf16 out) ----------------
__global__ __launch_bounds__(256) void k_wcomb(const float* __restrict__ Ws, const float* __restrict__ Wm,
                                               u16* __restrict__ wcomb)
{
  __shared__ float WmS[96][128];
  __shared__ float WsS[64][96];
  int tid=threadIdx.x;
  int e = blockIdx.x/12, dt = blockIdx.x%12;
  int d0 = dt*64;
  int s = tid&127, dh = tid>>7;
  float acc[32];
  #pragma unroll
  for(int i=0;i<32;i++) acc[i]=0.f;
  for(int c=0;c<8;c++){
    int c0=c*96;
    __syncthreads();
    for(int it=0; it<12; it++){
      int v=it*256+tid; int r=v>>5, c4=(v&31)*4;
      *reinterpret_cast<float4*>(&WmS[r][c4]) = *reinterpret_cast<const float4*>(Wm + (c0+r)*128 + c4);
    }
    for(int it=0; it<6; it++){
      int v=it*256+tid; int dl=v/24, c4=(v%24)*4;
      *reinterpret_cast<float4*>(&WsS[dl][c4]) = *reinterpret_cast<const float4*>(Ws + (d0+dl)*6144 + e*768 + c0 + c4);
    }
    __syncthreads();
    for(int d2=0; d2<96; d2++){
      float wm = WmS[d2][s];
      #pragma unroll
      for(int ds=0; ds<32; ds++) acc[ds] += WsS[dh*32+ds][d2]*wm;
    }
  }
  for(int ds=0; ds<32; ds++){
    int d = d0 + dh*32 + ds;
    wcomb[d*1024 + e*128 + s] = f2b(acc[ds]);
  }
}

// ---------------- routing softmax + q = W_ih@(Wi@h + bi) ----------------
__global__ __launch_bounds__(256) void k_route(const float* __restrict__ hseq, const float* __restrict__ ek,
                                               const float* __restrict__ Wi, const float* __restrict__ bi,
                                               const float* __restrict__ Wih,
                                               float* __restrict__ qws, float* __restrict__ out)
{
  __shared__ float hrow[8][768];
  __shared__ float projS[8][128];
  __shared__ float lgs[8][8];
  int tid=threadIdx.x;
  int row0 = blockIdx.x*8;
  for(int it=0; it<6; it++){
    int v=it*256+tid; int r=v/192, c4=(v%192)*4;
    *reinterpret_cast<float4*>(&hrow[r][c4]) = *reinterpret_cast<const float4*>(hseq + (row0+r)*768 + c4);
  }
  __syncthreads();
  if(tid<64){
    int r=tid>>3, e=tid&7;
    float acc=0.f;
    for(int k0=0;k0<768;k0+=4){
      float4 u=*reinterpret_cast<const float4*>(ek + e*768 + k0);
      const float* h=&hrow[r][k0];
      acc += u.x*h[0]+u.y*h[1]+u.z*h[2]+u.w*h[3];
    }
    lgs[r][e] = acc * (1.0f/27.712812921102035f);
  }
  __syncthreads();
  if(tid<8){
    int r=tid;
    float l[8], m=-1e30f;
    #pragma unroll
    for(int e=0;e<8;e++){ l[e]=lgs[r][e]; m=fmaxf(m,l[e]); }
    float s=0.f;
    #pragma unroll
    for(int e=0;e<8;e++){ l[e]=__builtin_amdgcn_exp2f(1.4426950408889634f*(l[e]-m)); s+=l[e]; }
    float inv=__builtin_amdgcn_rcpf(s);
    #pragma unroll
    for(int e=0;e<8;e++){
      out[OUT_ROUTE + (row0+r)*8 + e] = l[e]*inv;
    }
  }
  // proj = Wi@h + bi
  {
    int j=tid&127, rh=tid>>7;
    float facc[4];
    float bj=bi[j];
    #pragma unroll
    for(int rr=0;rr<4;rr++) facc[rr]=bj;
    for(int k0=0;k0<768;k0+=4){
      float4 u=*reinterpret_cast<const float4*>(Wi + j*768 + k0);
      #pragma unroll
      for(int rr=0;rr<4;rr++){
        const float* h=&hrow[rh*4+rr][k0];
        facc[rr] += u.x*h[0]+u.y*h[1]+u.z*h[2]+u.w*h[3];
      }
    }
    #pragma unroll
    for(int rr=0;rr<4;rr++) projS[rh*4+rr][j]=facc[rr];
  }
  __syncthreads();
  // q = W_ih @ proj
  for(int p=0;p<12;p++){
    int task=p*256+tid;
    int r=task/384, jq=task%384;
    float acc=0.f;
    for(int k0=0;k0<128;k0+=4){
      float4 u=*reinterpret_cast<const float4*>(Wih + jq*128 + k0);
      const float* pr=&projS[r][k0];
      acc += u.x*pr[0]+u.y*pr[1]+u.z*pr[2]+u.w*pr[3];
    }
    qws[(row0+r)*384 + jq]=acc;
  }
}

// ---------------- sequential GRU scan: 4 wgs x 16 rows, MFMA recurrent matmul ----------------
__global__ __launch_bounds__(512,1) void k_scan(const float* __restrict__ Whh, const float* __restrict__ bih,
                                                const float* __restrict__ bhh, const float* __restrict__ state0,
                                                const float* __restrict__ qws, float* __restrict__ out,
                                                u16* __restrict__ shadow)
{
  __shared__ u16 hbf[2][16][136];
  __shared__ float hf[2][16][132];
  __shared__ float qv[2][2][384];
  __shared__ float wvS[2][2][8];
  int tid=threadIdx.x;
  int w=tid>>6, L=tid&63, q4=L>>4, il=L&15;
  int b0=blockIdx.x*2;
  int ch=w*16+il;              // channel (state dim) this lane's gate columns refer to
  // persistent B-fragments of W_hh (rows = gate cols, [N=384][K=128] row-major), cvt f32->bf16
  bf16x8 bfr[3][4];
  float bihv[3], bhhv[3];
  #pragma unroll
  for(int g=0; g<3; g++){
    int ng = g*128 + ch;
    #pragma unroll
    for(int kt=0; kt<4; kt++){
      const float* p = Whh + ng*128 + kt*32 + q4*8;
      u16 tmp[8];
      #pragma unroll
      for(int j=0;j<8;j++) tmp[j]=f2b(p[j]);
      bf16x8 fr; __builtin_memcpy(&fr, tmp, 16);
      bfr[g][kt]=fr;
    }
    bihv[g]=bih[ng]; bhhv[g]=bhh[ng];
  }
  // init h (broadcast state0 over batch rows)
  for(int idx=tid; idx<2048; idx+=512){
    int m=idx>>7, c=idx&127;
    float s0v=state0[(m&7)*128+c];
    hf[0][m][c]=s0v; hbf[0][m][c]=f2b(s0v);
  }
  // init q,w for t=0
  {
    int bl=tid/384, col=tid-bl*384;
    qv[0][bl][col]=qws[((b0+bl)*1024+0)*384+col];
    if(tid<256) qv[0][1][tid+128]=qws[((b0+1)*1024+0)*384+(tid+128)];
    if(tid>=496){ int j=tid-496; wvS[0][j>>3][j&7]=out[OUT_ROUTE+((b0+(j>>3))*1024+0)*8+(j&7)]; }
  }
  __syncthreads();
  int bl1=tid/384, col1=tid-bl1*384;
  #pragma unroll 1
  for(int t=0;t<1024;t++){
    int buf=t&1, nxt=buf^1;
    int tq = (t<1023)? t+1 : 1023;
    // prefetch next step's q and route weights
    float pf1 = qws[((b0+bl1)*1024+tq)*384+col1];
    float pf2 = 0.f;
    if(tid<256) pf2 = qws[((b0+1)*1024+tq)*384+(tid+128)];
    float pfw = 0.f;
    if(tid>=496){ int j=tid-496; pfw=out[OUT_ROUTE+((b0+(j>>3))*1024+tq)*8+(j&7)]; }
    // A fragments (h in bf16)
    bf16x8 af[4];
    #pragma unroll
    for(int kt=0;kt<4;kt++)
      af[kt]=__builtin_bit_cast(bf16x8, *reinterpret_cast<const uint4*>(&hbf[buf][il][kt*32+q4*8]));
    float hp[4];
    #pragma unroll
    for(int i=0;i<4;i++) hp[i]=hf[buf][q4*4+i][ch];
    const f32x4 fz = {0.f,0.f,0.f,0.f};
    f32x4 acc0=fz, acc1=fz, acc2=fz;
    #pragma unroll
    for(int kt=0;kt<4;kt++){
      acc0=__builtin_amdgcn_mfma_f32_16x16x32_bf16(af[kt],bfr[0][kt],acc0,0,0,0);
      acc1=__builtin_amdgcn_mfma_f32_16x16x32_bf16(af[kt],bfr[1][kt],acc1,0,0,0);
      acc2=__builtin_amdgcn_mfma_f32_16x16x32_bf16(af[kt],bfr[2][kt],acc2,0,0,0);
    }
    #pragma unroll
    for(int i=0;i<4;i++){
      int m=q4*4+i; int bl=m>>3; int e=m&7;
      float wv_=wvS[buf][bl][e];
      float qr=qv[buf][bl][ch], qz=qv[buf][bl][128+ch], qn=qv[buf][bl][256+ch];
      float r=sigf(acc0[i]+bhhv[0]+wv_*qr+bihv[0]);
      float z=sigf(acc1[i]+bhhv[1]+wv_*qz+bihv[1]);
      float n=tanh_(wv_*qn+bihv[2]+r*(acc2[i]+bhhv[2]));
      float hn=n+z*(hp[i]-n);
      hf[nxt][m][ch]=hn;
      u16 hb=f2b(hn);
      hbf[nxt][m][ch]=hb;
      int gidx=(((b0+bl)*1024+t)*8+e)*128+ch;
      out[OUT_STATE + gidx]=hn;
      shadow[gidx]=hb;
    }
    qv[nxt][bl1][col1]=pf1;
    if(tid<256) qv[nxt][1][tid+128]=pf2;
    if(tid>=496){ int j=tid-496; wvS[nxt][j>>3][j&7]=pfw; }
    __syncthreads();
  }
}

// ---------------- memory_stack + head hidden (GEMM [65536x128]@[128x960]) ----------------
__global__ __launch_bounds__(256) void k_mem(const u16* __restrict__ state, const u16* __restrict__ wcat,
                                             const float* __restrict__ bcat,
                                             float* __restrict__ memout, u16* __restrict__ hdn)
{
  __shared__ u16 As[128][136];
  __shared__ u16 Bs[96][136];
  int tid=threadIdx.x;
  int bx=blockIdx.x, ny=blockIdx.y;
  for(int it=0;it<8;it++){
    int v=it*256+tid; int r=v>>4, c8=(v&15)*8;
    *reinterpret_cast<uint4*>(&As[r][c8]) = *reinterpret_cast<const uint4*>(state + (bx*128+r)*128 + c8);
  }
  for(int it=0;it<6;it++){
    int v=it*256+tid; int r=v>>4, c8=(v&15)*8;
    *reinterpret_cast<uint4*>(&Bs[r][c8]) = *reinterpret_cast<const uint4*>(wcat + (ny*96+r)*128 + c8);
  }
  __syncthreads();
  int w=tid>>6, L=tid&63, q4=L>>4, il=L&15;
  int msub=w*32;
  bf16x8 af[2][4];
  #pragma unroll
  for(int tm=0;tm<2;tm++)
    #pragma unroll
    for(int kt=0;kt<4;kt++)
      af[tm][kt]=__builtin_bit_cast(bf16x8,*reinterpret_cast<const uint4*>(&As[msub+tm*16+il][kt*32+q4*8]));
  const f32x4 fz = {0.f,0.f,0.f,0.f};
  f32x4 acc[2][6];
  #pragma unroll
  for(int tm=0;tm<2;tm++){
    #pragma unroll
    for(int tn=0;tn<6;tn++) acc[tm][tn]=fz;
  }
  #pragma unroll
  for(int tn=0;tn<6;tn++){
    bf16x8 bf[4];
    #pragma unroll
    for(int kt=0;kt<4;kt++)
      bf[kt]=__builtin_bit_cast(bf16x8,*reinterpret_cast<const uint4*>(&Bs[tn*16+il][kt*32+q4*8]));
    #pragma unroll
    for(int tm=0;tm<2;tm++){
      #pragma unroll
      for(int kt=0;kt<4;kt++)
        acc[tm][tn]=__builtin_amdgcn_mfma_f32_16x16x32_bf16(af[tm][kt],bf[kt],acc[tm][tn],0,0,0);
    }
  }
  #pragma unroll
  for(int tm=0;tm<2;tm++){
    #pragma unroll
    for(int tn=0;tn<6;tn++){
      int col=ny*96+tn*16+il;
      float bias=bcat[col];
      #pragma unroll
      for(int i=0;i<4;i++){
        int row=bx*128+msub+tm*16+q4*4+i;
        float val=acc[tm][tn][i]+bias;
        if(ny<8) memout[row*768+col]=val;
        else hdn[row*192+(col-768)]=f2b(geluf(val));
      }
    }
  }
}

// ---------------- pooled = state_flat[8192x1024] @ Wcomb.T + b_comb ----------------
__global__ __launch_bounds__(256) void k_pool(const u16* __restrict__ state, const u16* __restrict__ wcomb,
                                              const float* __restrict__ bcomb, float* __restrict__ pooled)
{
  __shared__ u16 As[128][136];
  __shared__ u16 Bs[96][136];
  int tid=threadIdx.x;
  int bx=blockIdx.x, ny=blockIdx.y;
  int w=tid>>6, L=tid&63, q4=L>>4, il=L&15;
  int msub=w*32;
  const f32x4 fz = {0.f,0.f,0.f,0.f};
  f32x4 acc[2][6];
  #pragma unroll
  for(int tm=0;tm<2;tm++){
    #pragma unroll
    for(int tn=0;tn<6;tn++) acc[tm][tn]=fz;
  }
  for(int kc=0;kc<8;kc++){
    __syncthreads();
    for(int it=0;it<8;it++){
      int v=it*256+tid; int r=v>>4, c8=(v&15)*8;
      *reinterpret_cast<uint4*>(&As[r][c8]) = *reinterpret_cast<const uint4*>(state + (bx*128+r)*1024 + kc*128 + c8);
    }
    for(int it=0;it<6;it++){
      int v=it*256+tid; int r=v>>4, c8=(v&15)*8;
      *reinterpret_cast<uint4*>(&Bs[r][c8]) = *reinterpret_cast<const uint4*>(wcomb + (ny*96+r)*1024 + kc*128 + c8);
    }
    __syncthreads();
    bf16x8 af[2][4];
    #pragma unroll
    for(int tm=0;tm<2;tm++)
      #pragma unroll
      for(int kt=0;kt<4;kt++)
        af[tm][kt]=__builtin_bit_cast(bf16x8,*reinterpret_cast<const uint4*>(&As[msub+tm*16+il][kt*32+q4*8]));
    #pragma unroll
    for(int tn=0;tn<6;tn++){
      bf16x8 bf[4];
      #pragma unroll
      for(int kt=0;kt<4;kt++)
        bf[kt]=__builtin_bit_cast(bf16x8,*reinterpret_cast<const uint4*>(&Bs[tn*16+il][kt*32+q4*8]));
      #pragma unroll
      for(int tm=0;tm<2;tm++){
        #pragma unroll
        for(int kt=0;kt<4;kt++)
          acc[tm][tn]=__builtin_amdgcn_mfma_f32_16x16x32_bf16(af[tm][kt],bf[kt],acc[tm][tn],0,0,0);
      }
    }
  }
  #pragma unroll
  for(int tm=0;tm<2;tm++){
    #pragma unroll
    for(int tn=0;tn<6;tn++){
      int col=ny*96+tn*16+il;
      float bias=bcomb[col];
      #pragma unroll
      for(int i=0;i<4;i++){
        int row=bx*128+msub+tm*16+q4*4+i;
        pooled[row*768+col]=acc[tm][tn][i]+bias;
      }
    }
  }
}

// ---------------- head second layer ----------------
__global__ __launch_bounds__(256) void k_heads(const u16* __restrict__ hdn,
                                               const float* __restrict__ Wh2, const float* __restrict__ bh2,
                                               const float* __restrict__ Wt2, const float* __restrict__ bt2,
                                               const float* __restrict__ Wv2, const float* __restrict__ bv2,
                                               float* __restrict__ out)
{
  int oid=blockIdx.x*256+threadIdx.x;
  int row=oid&65535, head=oid>>16;
  const float* w2 = (head==0)?Wh2:(head==1)?Wt2:Wv2;
  float b2 = ((head==0)?bh2:(head==1)?bt2:bv2)[0];
  float acc=0.f;
  const u16* src = hdn + row*192 + head*64;
  for(int j0=0;j0<64;j0+=8){
    uint4 hu=*reinterpret_cast<const uint4*>(src+j0);
    u16 hs[8]; __builtin_memcpy(hs,&hu,16);
    #pragma unroll
    for(int j=0;j<8;j++) acc+=b2f(hs[j])*w2[j0+j];
  }
  out[OUT_HOLD + head*65536 + row]=acc+b2;
}

extern "C" void kernel_launch(void* const* d_in, const int* in_sizes, int n_in,
                              void* d_out, int out_size, void* d_ws, size_t ws_size,
                              hipStream_t stream)
{
  const float* hseq=(const float*)d_in[0];
  const float* ek  =(const float*)d_in[1];
  const float* st0 =(const float*)d_in[2];
  const float* Wi  =(const float*)d_in[3];
  const float* bi  =(const float*)d_in[4];
  const float* Wih =(const float*)d_in[5];
  const float* Whh =(const float*)d_in[6];
  const float* bih =(const float*)d_in[7];
  const float* bhh =(const float*)d_in[8];
  const float* Wm  =(const float*)d_in[9];
  const float* bm  =(const float*)d_in[10];
  const float* Ws  =(const float*)d_in[11];
  const float* bs  =(const float*)d_in[12];
  const float* Wh1 =(const float*)d_in[13];
  const float* bh1 =(const float*)d_in[14];
  const float* Wh2 =(const float*)d_in[15];
  const float* bh2 =(const float*)d_in[16];
  const float* Wt1 =(const float*)d_in[17];
  const float* bt1 =(const float*)d_in[18];
  const float* Wt2 =(const float*)d_in[19];
  const float* bt2 =(const float*)d_in[20];
  const float* Wv1 =(const float*)d_in[21];
  const float* bv1 =(const float*)d_in[22];
  const float* Wv2 =(const float*)d_in[23];
  const float* bv2 =(const float*)d_in[24];
  float* out=(float*)d_out;
  char* ws=(char*)d_ws;
  float* qws  =(float*)ws;                 // 8192*384*4      = 12,582,912
  u16*  wcomb =(u16*)(ws+12582912);        // 768*1024*2      =  1,572,864  -> 14,155,776
  float* bcomb=(float*)(ws+14155776);      // 768*4           =      3,072  -> 14,158,848
  u16*  wcat  =(u16*)(ws+14158848);        // 960*128*2       =    245,760  -> 14,404,608
  float* bcat =(float*)(ws+14404608);      // 960*4           =      3,840  -> 14,408,448
  u16*  hdn   =(u16*)(ws+14408448);        // 65536*192*2     = 25,165,824  -> 39,574,272
  u16*  shadow=(u16*)(ws+39574272);        // 65536*128*2     = 16,777,216  -> 56,351,488

  hipLaunchKernelGGL(k_prep, dim3(128), dim3(256), 0, stream,
                     Ws,bs,bm,Wm,Wh1,bh1,Wt1,bt1,Wv1,bv1,wcat,bcat,bcomb);
  hipLaunchKernelGGL(k_wcomb, dim3(96), dim3(256), 0, stream, Ws,Wm,wcomb);
  hipLaunchKernelGGL(k_route, dim3(1024), dim3(256), 0, stream, hseq,ek,Wi,bi,Wih,qws,out);
  hipLaunchKernelGGL(k_scan, dim3(4), dim3(512), 0, stream, Whh,bih,bhh,st0,qws,out,shadow);
  hipLaunchKernelGGL(k_mem, dim3(512,10), dim3(256), 0, stream, shadow,wcat,bcat,out+OUT_MEM,hdn);
  hipLaunchKernelGGL(k_pool, dim3(64,8), dim3(256), 0, stream, shadow,wcomb,bcomb,out+OUT_POOLED);
  hipLaunchKernelGGL(k_heads, dim3(768), dim3(256), 0, stream, hdn,Wh2,bh2,Wt2,bt2,Wv2,bv2,out);
}

// Round 3
// 1853.874 us; speedup vs baseline: 1.1528x; 1.1528x over previous
//
#include <hip/hip_runtime.h>
#include <hip/hip_bf16.h>

typedef unsigned short u16;
typedef unsigned int u32;
typedef __bf16 bf16x8 __attribute__((ext_vector_type(8)));
typedef float f32x4 __attribute__((ext_vector_type(4)));

// output element offsets (f32 elements)
#define OUT_POOLED 0
#define OUT_MEM    6291456
#define OUT_STATE  56623104
#define OUT_HOLD   65011712
#define OUT_ROUTE  65208320

__device__ __forceinline__ float b2f(u16 u){ u32 v=((u32)u)<<16; float f; __builtin_memcpy(&f,&v,4); return f; }
__device__ __forceinline__ u16 f2b(float f){ __hip_bfloat16 h=__float2bfloat16(f); u16 r; __builtin_memcpy(&r,&h,2); return r; }
__device__ __forceinline__ float sigf(float x){ return __builtin_amdgcn_rcpf(1.0f+__builtin_amdgcn_exp2f(-1.4426950408889634f*x)); }
__device__ __forceinline__ float tanh_(float x){ return 1.0f-2.0f*__builtin_amdgcn_rcpf(1.0f+__builtin_amdgcn_exp2f(2.8853900817779268f*x)); }
__device__ __forceinline__ float geluf(float x){
  float z = 0.7071067811865476f*x;
  float az = __builtin_fabsf(z);
  float t = __builtin_amdgcn_rcpf(1.0f+0.3275911f*az);
  float p = t*(0.254829592f+t*(-0.284496736f+t*(1.421413741f+t*(-1.453152027f+t*1.061405429f))));
  float e = __builtin_amdgcn_exp2f(-1.4426950408889634f*az*az);
  float er = 1.0f-p*e;
  er = (z<0.0f)? -er : er;
  return 0.5f*x*(1.0f+er);
}

// ---------------- prep: wcat pack (bf16), bcat, b_comb ----------------
__global__ void k_prep(const float* __restrict__ Ws, const float* __restrict__ bs,
                       const float* __restrict__ bm, const float* __restrict__ Wm,
                       const float* __restrict__ Wh1, const float* __restrict__ bh1,
                       const float* __restrict__ Wt1, const float* __restrict__ bt1,
                       const float* __restrict__ Wv1, const float* __restrict__ bv1,
                       u16* __restrict__ wcat, float* __restrict__ bcat, float* __restrict__ bcomb)
{
  __shared__ float bmS[768];
  int tid = threadIdx.x;
  for(int i=tid;i<768;i+=256) bmS[i]=bm[i];
  __syncthreads();
  const int total = 768+960+122880;
  for(int idx = blockIdx.x*256+tid; idx<total; idx += gridDim.x*256){
    if(idx<768){
      int d=idx; float acc=bs[d];
      for(int e=0;e<8;e++){
        const float* row = Ws + d*6144 + e*768;
        for(int k0=0;k0<768;k0+=4){
          float4 u = *reinterpret_cast<const float4*>(row+k0);
          acc += u.x*bmS[k0]+u.y*bmS[k0+1]+u.z*bmS[k0+2]+u.w*bmS[k0+3];
        }
      }
      bcomb[d]=acc;
    } else if(idx<1728){
      int n=idx-768;
      float v;
      if(n<768) v=bm[n];
      else { int j=n-768; v = (j<64)? bh1[j] : (j<128)? bt1[j-64] : bv1[j-128]; }
      bcat[n]=v;
    } else {
      int c=idx-1728; int n=c>>7, k=c&127;
      float v;
      if(n<768) v=Wm[n*128+k];
      else if(n<832) v=Wh1[(n-768)*128+k];
      else if(n<896) v=Wt1[(n-832)*128+k];
      else v=Wv1[(n-896)*128+k];
      wcat[c]=f2b(v);
    }
  }
}

// ---------------- Wcomb[d][e*128+s] = sum_d2 Ws[d][e*768+d2]*Wm[d2][s] (bf16 out) ----------------
__global__ __launch_bounds__(256) void k_wcomb(const float* __restrict__ Ws, const float* __restrict__ Wm,
                                               u16* __restrict__ wcomb)
{
  __shared__ float WmS[96][128];
  __shared__ float WsS[64][96];
  int tid=threadIdx.x;
  int e = blockIdx.x/12, dt = blockIdx.x%12;
  int d0 = dt*64;
  int s = tid&127, dh = tid>>7;
  float acc[32];
  #pragma unroll
  for(int i=0;i<32;i++) acc[i]=0.f;
  for(int c=0;c<8;c++){
    int c0=c*96;
    __syncthreads();
    for(int it=0; it<12; it++){
      int v=it*256+tid; int r=v>>5, c4=(v&31)*4;
      *reinterpret_cast<float4*>(&WmS[r][c4]) = *reinterpret_cast<const float4*>(Wm + (c0+r)*128 + c4);
    }
    for(int it=0; it<6; it++){
      int v=it*256+tid; int dl=v/24, c4=(v%24)*4;
      *reinterpret_cast<float4*>(&WsS[dl][c4]) = *reinterpret_cast<const float4*>(Ws + (d0+dl)*6144 + e*768 + c0 + c4);
    }
    __syncthreads();
    for(int d2=0; d2<96; d2++){
      float wm = WmS[d2][s];
      #pragma unroll
      for(int ds=0; ds<32; ds++) acc[ds] += WsS[dh*32+ds][d2]*wm;
    }
  }
  for(int ds=0; ds<32; ds++){
    int d = d0 + dh*32 + ds;
    wcomb[d*1024 + e*128 + s] = f2b(acc[ds]);
  }
}

// ---------------- routing softmax + q = W_ih@(Wi@h + bi) ----------------
__global__ __launch_bounds__(256) void k_route(const float* __restrict__ hseq, const float* __restrict__ ek,
                                               const float* __restrict__ Wi, const float* __restrict__ bi,
                                               const float* __restrict__ Wih,
                                               float* __restrict__ qws, float* __restrict__ out)
{
  __shared__ float hrow[8][768];
  __shared__ float projS[8][128];
  __shared__ float lgs[8][8];
  int tid=threadIdx.x;
  int row0 = blockIdx.x*8;
  for(int it=0; it<6; it++){
    int v=it*256+tid; int r=v/192, c4=(v%192)*4;
    *reinterpret_cast<float4*>(&hrow[r][c4]) = *reinterpret_cast<const float4*>(hseq + (row0+r)*768 + c4);
  }
  __syncthreads();
  if(tid<64){
    int r=tid>>3, e=tid&7;
    float acc=0.f;
    for(int k0=0;k0<768;k0+=4){
      float4 u=*reinterpret_cast<const float4*>(ek + e*768 + k0);
      const float* h=&hrow[r][k0];
      acc += u.x*h[0]+u.y*h[1]+u.z*h[2]+u.w*h[3];
    }
    lgs[r][e] = acc * (1.0f/27.712812921102035f);
  }
  __syncthreads();
  if(tid<8){
    int r=tid;
    float l[8], m=-1e30f;
    #pragma unroll
    for(int e=0;e<8;e++){ l[e]=lgs[r][e]; m=fmaxf(m,l[e]); }
    float s=0.f;
    #pragma unroll
    for(int e=0;e<8;e++){ l[e]=__builtin_amdgcn_exp2f(1.4426950408889634f*(l[e]-m)); s+=l[e]; }
    float inv=__builtin_amdgcn_rcpf(s);
    #pragma unroll
    for(int e=0;e<8;e++){
      out[OUT_ROUTE + (row0+r)*8 + e] = l[e]*inv;
    }
  }
  // proj = Wi@h + bi
  {
    int j=tid&127, rh=tid>>7;
    float facc[4];
    float bj=bi[j];
    #pragma unroll
    for(int rr=0;rr<4;rr++) facc[rr]=bj;
    for(int k0=0;k0<768;k0+=4){
      float4 u=*reinterpret_cast<const float4*>(Wi + j*768 + k0);
      #pragma unroll
      for(int rr=0;rr<4;rr++){
        const float* h=&hrow[rh*4+rr][k0];
        facc[rr] += u.x*h[0]+u.y*h[1]+u.z*h[2]+u.w*h[3];
      }
    }
    #pragma unroll
    for(int rr=0;rr<4;rr++) projS[rh*4+rr][j]=facc[rr];
  }
  __syncthreads();
  // q = W_ih @ proj
  for(int p=0;p<12;p++){
    int task=p*256+tid;
    int r=task/384, jq=task%384;
    float acc=0.f;
    for(int k0=0;k0<128;k0+=4){
      float4 u=*reinterpret_cast<const float4*>(Wih + jq*128 + k0);
      const float* pr=&projS[r][k0];
      acc += u.x*pr[0]+u.y*pr[1]+u.z*pr[2]+u.w*pr[3];
    }
    qws[(row0+r)*384 + jq]=acc;
  }
}

// ---------------- gpre[bt][e][col] = w[b,t,e]*q[b,t,col] + bih[col] (+bhh[col] for col<256), bf16 ----------------
__global__ __launch_bounds__(256) void k_gpre(const float* __restrict__ qws, const float* __restrict__ out,
                                              const float* __restrict__ bih, const float* __restrict__ bhh,
                                              u16* __restrict__ gpre)
{
  __shared__ float wS[8];
  __shared__ float qS[384];
  int tid=threadIdx.x;
  int bt=blockIdx.x;
  if(tid<8) wS[tid]=out[OUT_ROUTE + bt*8 + tid];
  if(tid>=128 && tid<224){ int j=tid-128; *reinterpret_cast<float4*>(&qS[j*4]) = *reinterpret_cast<const float4*>(qws + bt*384 + j*4); }
  __syncthreads();
  #pragma unroll
  for(int k=0;k<12;k++){
    int o=k*256+tid;
    int e=o/384, col=o-e*384;
    float bias = bih[col] + ((col<256)? bhh[col] : 0.f);
    gpre[(size_t)bt*3072 + o] = f2b(wS[e]*qS[col] + bias);
  }
}

// ---------------- sequential GRU scan: 4 wgs x 16 rows, MFMA recurrent matmul ----------------
// lane (w,q4,il): ch=w*16+il; rows m=q4*4+i; bl=q4>>1; e=(q4&1)*4+i. hp carried in registers.
#define SCAN_STEP(BUF, NXT, CUR, NEXT)                                                      \
  {                                                                                         \
    _Pragma("unroll")                                                                       \
    for(int i=0;i<4;i++){                                                                   \
      _Pragma("unroll")                                                                     \
      for(int g=0;g<3;g++) NEXT[i*3+g]=b2f(gp[i*384+g*128]);                                \
    }                                                                                       \
    gp += 3072;                                                                             \
    bf16x8 af[4];                                                                           \
    _Pragma("unroll")                                                                       \
    for(int kt=0;kt<4;kt++)                                                                 \
      af[kt]=__builtin_bit_cast(bf16x8, *reinterpret_cast<const uint4*>(&hbf[BUF][il][kt*32+q4*8])); \
    f32x4 acc0={0.f,0.f,0.f,0.f}, acc1={0.f,0.f,0.f,0.f}, acc2={0.f,0.f,0.f,0.f};           \
    _Pragma("unroll")                                                                       \
    for(int kt=0;kt<4;kt++){                                                                \
      acc0=__builtin_amdgcn_mfma_f32_16x16x32_bf16(af[kt],bfr0[kt],acc0,0,0,0);             \
      acc1=__builtin_amdgcn_mfma_f32_16x16x32_bf16(af[kt],bfr1[kt],acc1,0,0,0);             \
      acc2=__builtin_amdgcn_mfma_f32_16x16x32_bf16(af[kt],bfr2[kt],acc2,0,0,0);             \
    }                                                                                       \
    _Pragma("unroll")                                                                       \
    for(int i=0;i<4;i++){                                                                   \
      float r=sigf(acc0[i]+CUR[i*3+0]);                                                     \
      float z=sigf(acc1[i]+CUR[i*3+1]);                                                     \
      float n=tanh_(CUR[i*3+2]+r*(acc2[i]+bhhn));                                           \
      float hn=n+z*(hp[i]-n);                                                               \
      hp[i]=hn;                                                                             \
      u16 hb=f2b(hn);                                                                       \
      hbf[NXT][q4*4+i][ch]=hb;                                                              \
      sbase[i*128]=hb;                                                                      \
    }                                                                                       \
    sbase += 1024;                                                                          \
    __syncthreads();                                                                        \
  }

__global__ __launch_bounds__(512,1) void k_scan(const float* __restrict__ Whh, const float* __restrict__ bhh,
                                                const float* __restrict__ state0,
                                                const u16* __restrict__ gpre, u16* __restrict__ shadow)
{
  __shared__ u16 hbf[2][16][136];
  int tid=threadIdx.x;
  int w=tid>>6, L=tid&63, q4=L>>4, il=L&15;
  int b0=blockIdx.x*2;
  int ch=w*16+il;
  int bl=q4>>1, e0=(q4&1)*4;
  // persistent B-fragments of W_hh (N=384 gate cols x K=128), cvt f32->bf16
  bf16x8 bfr0[4], bfr1[4], bfr2[4];
  #pragma unroll
  for(int kt=0; kt<4; kt++){
    u16 t0[8],t1[8],t2[8];
    #pragma unroll
    for(int j=0;j<8;j++){
      t0[j]=f2b(Whh[(0*128+ch)*128 + kt*32 + q4*8 + j]);
      t1[j]=f2b(Whh[(1*128+ch)*128 + kt*32 + q4*8 + j]);
      t2[j]=f2b(Whh[(2*128+ch)*128 + kt*32 + q4*8 + j]);
    }
    __builtin_memcpy(&bfr0[kt],t0,16);
    __builtin_memcpy(&bfr1[kt],t1,16);
    __builtin_memcpy(&bfr2[kt],t2,16);
  }
  float bhhn = bhh[256+ch];
  // register-carried h (f32) for this lane's 4 (row,ch) cells
  float hp[4];
  #pragma unroll
  for(int i=0;i<4;i++) hp[i]=state0[(e0+i)*128+ch];
  // init bf16 h tile
  for(int idx=tid; idx<2048; idx+=512){
    int m=idx>>7, c=idx&127;
    hbf[0][m][c]=f2b(state0[(m&7)*128+c]);
  }
  // per-lane streaming pointers
  const u16* gp = gpre + ((size_t)(b0+bl)*1024*8 + e0)*384 + ch;
  u16* sbase = shadow + ((size_t)(b0+bl)*1024*8 + e0)*128 + ch;
  float ga[12], gb[12];
  #pragma unroll
  for(int i=0;i<4;i++){
    #pragma unroll
    for(int g=0;g<3;g++) ga[i*3+g]=b2f(gp[i*384+g*128]);
  }
  gp += 3072;
  __syncthreads();
  #pragma unroll 1
  for(int t2=0;t2<512;t2++){
    SCAN_STEP(0,1,ga,gb)
    SCAN_STEP(1,0,gb,ga)
  }
}

// ---------------- expand bf16 shadow -> f32 OUT_STATE ----------------
__global__ __launch_bounds__(256) void k_expand(const u16* __restrict__ sh, float* __restrict__ o)
{
  int idx=(blockIdx.x*256+threadIdx.x)*4;
  uint2 u=*reinterpret_cast<const uint2*>(sh+idx);
  float4 f;
  f.x=b2f((u16)(u.x&0xffffu)); f.y=b2f((u16)(u.x>>16));
  f.z=b2f((u16)(u.y&0xffffu)); f.w=b2f((u16)(u.y>>16));
  *reinterpret_cast<float4*>(o+idx)=f;
}

// ---------------- memory_stack + head hidden (GEMM [65536x128]@[128x960]) ----------------
__global__ __launch_bounds__(256) void k_mem(const u16* __restrict__ state, const u16* __restrict__ wcat,
                                             const float* __restrict__ bcat,
                                             float* __restrict__ memout, u16* __restrict__ hdn)
{
  __shared__ u16 As[128][136];
  __shared__ u16 Bs[96][136];
  int tid=threadIdx.x;
  int bx=blockIdx.x, ny=blockIdx.y;
  for(int it=0;it<8;it++){
    int v=it*256+tid; int r=v>>4, c8=(v&15)*8;
    *reinterpret_cast<uint4*>(&As[r][c8]) = *reinterpret_cast<const uint4*>(state + (bx*128+r)*128 + c8);
  }
  for(int it=0;it<6;it++){
    int v=it*256+tid; int r=v>>4, c8=(v&15)*8;
    *reinterpret_cast<uint4*>(&Bs[r][c8]) = *reinterpret_cast<const uint4*>(wcat + (ny*96+r)*128 + c8);
  }
  __syncthreads();
  int w=tid>>6, L=tid&63, q4=L>>4, il=L&15;
  int msub=w*32;
  bf16x8 af[2][4];
  #pragma unroll
  for(int tm=0;tm<2;tm++)
    #pragma unroll
    for(int kt=0;kt<4;kt++)
      af[tm][kt]=__builtin_bit_cast(bf16x8,*reinterpret_cast<const uint4*>(&As[msub+tm*16+il][kt*32+q4*8]));
  const f32x4 fz = {0.f,0.f,0.f,0.f};
  f32x4 acc[2][6];
  #pragma unroll
  for(int tm=0;tm<2;tm++){
    #pragma unroll
    for(int tn=0;tn<6;tn++) acc[tm][tn]=fz;
  }
  #pragma unroll
  for(int tn=0;tn<6;tn++){
    bf16x8 bf[4];
    #pragma unroll
    for(int kt=0;kt<4;kt++)
      bf[kt]=__builtin_bit_cast(bf16x8,*reinterpret_cast<const uint4*>(&Bs[tn*16+il][kt*32+q4*8]));
    #pragma unroll
    for(int tm=0;tm<2;tm++){
      #pragma unroll
      for(int kt=0;kt<4;kt++)
        acc[tm][tn]=__builtin_amdgcn_mfma_f32_16x16x32_bf16(af[tm][kt],bf[kt],acc[tm][tn],0,0,0);
    }
  }
  #pragma unroll
  for(int tm=0;tm<2;tm++){
    #pragma unroll
    for(int tn=0;tn<6;tn++){
      int col=ny*96+tn*16+il;
      float bias=bcat[col];
      #pragma unroll
      for(int i=0;i<4;i++){
        int row=bx*128+msub+tm*16+q4*4+i;
        float val=acc[tm][tn][i]+bias;
        if(ny<8) memout[row*768+col]=val;
        else hdn[row*192+(col-768)]=f2b(geluf(val));
      }
    }
  }
}

// ---------------- pooled = state_flat[8192x1024] @ Wcomb.T + b_comb ----------------
__global__ __launch_bounds__(256) void k_pool(const u16* __restrict__ state, const u16* __restrict__ wcomb,
                                              const float* __restrict__ bcomb, float* __restrict__ pooled)
{
  __shared__ u16 As[128][136];
  __shared__ u16 Bs[96][136];
  int tid=threadIdx.x;
  int bx=blockIdx.x, ny=blockIdx.y;
  int w=tid>>6, L=tid&63, q4=L>>4, il=L&15;
  int msub=w*32;
  const f32x4 fz = {0.f,0.f,0.f,0.f};
  f32x4 acc[2][6];
  #pragma unroll
  for(int tm=0;tm<2;tm++){
    #pragma unroll
    for(int tn=0;tn<6;tn++) acc[tm][tn]=fz;
  }
  for(int kc=0;kc<8;kc++){
    __syncthreads();
    for(int it=0;it<8;it++){
      int v=it*256+tid; int r=v>>4, c8=(v&15)*8;
      *reinterpret_cast<uint4*>(&As[r][c8]) = *reinterpret_cast<const uint4*>(state + (bx*128+r)*1024 + kc*128 + c8);
    }
    for(int it=0;it<6;it++){
      int v=it*256+tid; int r=v>>4, c8=(v&15)*8;
      *reinterpret_cast<uint4*>(&Bs[r][c8]) = *reinterpret_cast<const uint4*>(wcomb + (ny*96+r)*1024 + kc*128 + c8);
    }
    __syncthreads();
    bf16x8 af[2][4];
    #pragma unroll
    for(int tm=0;tm<2;tm++)
      #pragma unroll
      for(int kt=0;kt<4;kt++)
        af[tm][kt]=__builtin_bit_cast(bf16x8,*reinterpret_cast<const uint4*>(&As[msub+tm*16+il][kt*32+q4*8]));
    #pragma unroll
    for(int tn=0;tn<6;tn++){
      bf16x8 bf[4];
      #pragma unroll
      for(int kt=0;kt<4;kt++)
        bf[kt]=__builtin_bit_cast(bf16x8,*reinterpret_cast<const uint4*>(&Bs[tn*16+il][kt*32+q4*8]));
      #pragma unroll
      for(int tm=0;tm<2;tm++){
        #pragma unroll
        for(int kt=0;kt<4;kt++)
          acc[tm][tn]=__builtin_amdgcn_mfma_f32_16x16x32_bf16(af[tm][kt],bf[kt],acc[tm][tn],0,0,0);
      }
    }
  }
  #pragma unroll
  for(int tm=0;tm<2;tm++){
    #pragma unroll
    for(int tn=0;tn<6;tn++){
      int col=ny*96+tn*16+il;
      float bias=bcomb[col];
      #pragma unroll
      for(int i=0;i<4;i++){
        int row=bx*128+msub+tm*16+q4*4+i;
        pooled[row*768+col]=acc[tm][tn][i]+bias;
      }
    }
  }
}

// ---------------- head second layer ----------------
__global__ __launch_bounds__(256) void k_heads(const u16* __restrict__ hdn,
                                               const float* __restrict__ Wh2, const float* __restrict__ bh2,
                                               const float* __restrict__ Wt2, const float* __restrict__ bt2,
                                               const float* __restrict__ Wv2, const float* __restrict__ bv2,
                                               float* __restrict__ out)
{
  int oid=blockIdx.x*256+threadIdx.x;
  int row=oid&65535, head=oid>>16;
  const float* w2 = (head==0)?Wh2:(head==1)?Wt2:Wv2;
  float b2 = ((head==0)?bh2:(head==1)?bt2:bv2)[0];
  float acc=0.f;
  const u16* src = hdn + row*192 + head*64;
  for(int j0=0;j0<64;j0+=8){
    uint4 hu=*reinterpret_cast<const uint4*>(src+j0);
    u16 hs[8]; __builtin_memcpy(hs,&hu,16);
    #pragma unroll
    for(int j=0;j<8;j++) acc+=b2f(hs[j])*w2[j0+j];
  }
  out[OUT_HOLD + head*65536 + row]=acc+b2;
}

extern "C" void kernel_launch(void* const* d_in, const int* in_sizes, int n_in,
                              void* d_out, int out_size, void* d_ws, size_t ws_size,
                              hipStream_t stream)
{
  const float* hseq=(const float*)d_in[0];
  const float* ek  =(const float*)d_in[1];
  const float* st0 =(const float*)d_in[2];
  const float* Wi  =(const float*)d_in[3];
  const float* bi  =(const float*)d_in[4];
  const float* Wih =(const float*)d_in[5];
  const float* Whh =(const float*)d_in[6];
  const float* bih =(const float*)d_in[7];
  const float* bhh =(const float*)d_in[8];
  const float* Wm  =(const float*)d_in[9];
  const float* bm  =(const float*)d_in[10];
  const float* Ws  =(const float*)d_in[11];
  const float* bs  =(const float*)d_in[12];
  const float* Wh1 =(const float*)d_in[13];
  const float* bh1 =(const float*)d_in[14];
  const float* Wh2 =(const float*)d_in[15];
  const float* bh2 =(const float*)d_in[16];
  const float* Wt1 =(const float*)d_in[17];
  const float* bt1 =(const float*)d_in[18];
  const float* Wt2 =(const float*)d_in[19];
  const float* bt2 =(const float*)d_in[20];
  const float* Wv1 =(const float*)d_in[21];
  const float* bv1 =(const float*)d_in[22];
  const float* Wv2 =(const float*)d_in[23];
  const float* bv2 =(const float*)d_in[24];
  float* out=(float*)d_out;
  char* ws=(char*)d_ws;
  float* qws  =(float*)ws;                 // 8192*384*4          = 12,582,912
  u16*  gpre  =(u16*)(ws+12582912);        // 65536*384*2 + 16K   = 50,348,032  -> 62,930,944
  u16*  wcomb =(u16*)(ws+62930944);        // 768*1024*2          =  1,572,864  -> 64,503,808
  float* bcomb=(float*)(ws+64503808);      // 768*4               =      3,072  -> 64,506,880
  u16*  wcat  =(u16*)(ws+64506880);        // 960*128*2           =    245,760  -> 64,752,640
  float* bcat =(float*)(ws+64752640);      // 960*4               =      3,840  -> 64,756,480
  u16*  hdn   =(u16*)(ws+64756480);        // 65536*192*2         = 25,165,824  -> 89,922,304
  u16*  shadow=(u16*)(ws+89922304);        // 65536*128*2         = 16,777,216  -> 106,699,520

  hipLaunchKernelGGL(k_prep, dim3(128), dim3(256), 0, stream,
                     Ws,bs,bm,Wm,Wh1,bh1,Wt1,bt1,Wv1,bv1,wcat,bcat,bcomb);
  hipLaunchKernelGGL(k_wcomb, dim3(96), dim3(256), 0, stream, Ws,Wm,wcomb);
  hipLaunchKernelGGL(k_route, dim3(1024), dim3(256), 0, stream, hseq,ek,Wi,bi,Wih,qws,out);
  hipLaunchKernelGGL(k_gpre, dim3(8192), dim3(256), 0, stream, qws,out,bih,bhh,gpre);
  hipLaunchKernelGGL(k_scan, dim3(4), dim3(512), 0, stream, Whh,bhh,st0,gpre,shadow);
  hipLaunchKernelGGL(k_expand, dim3(8192), dim3(256), 0, stream, shadow,out+OUT_STATE);
  hipLaunchKernelGGL(k_mem, dim3(512,10), dim3(256), 0, stream, shadow,wcat,bcat,out+OUT_MEM,hdn);
  hipLaunchKernelGGL(k_pool, dim3(64,8), dim3(256), 0, stream, shadow,wcomb,bcomb,out+OUT_POOLED);
  hipLaunchKernelGGL(k_heads, dim3(768), dim3(256), 0, stream, hdn,Wh2,bh2,Wt2,bt2,Wv2,bv2,out);
}